// Round 17
// baseline (29.019 us; speedup 1.0000x reference)
//
#include <hip/hip_runtime.h>
#include <hip/hip_bf16.h>

constexpr int S  = 256;
constexpr int D  = 768;
constexpr int KQ = 4;          // K slices
constexpr int KS = D / KQ;     // 192 per slice
constexpr int CH = 96;         // staged chunk width (2 chunks per slice)
constexpr int GROWS = KQ * S;  // 1024 floats: G[((batch*256+row)*4+kq)*256+col]

typedef _Float16 half8  __attribute__((ext_vector_type(8)));
typedef _Float16 half4v __attribute__((ext_vector_type(4)));
typedef float    f32x4  __attribute__((ext_vector_type(4)));

// Lower-triangle 64x64 tile positions (ti >= tj) of the 4x4 tile grid.
__device__ const int TI_MAP[10] = {0,1,1,2,2,2,3,3,3,3};
__device__ const int TJ_MAP[10] = {0,0,1,0,1,2,0,1,2,3};

// Gram via MFMA (r15-validated verbatim): triangle tiles, fused fp16 hi/lo
// split, diag B->A alias, fused X@W partials, 2x2 micro-tile, KQ=4 with two
// register-prefetched 96-chunks. Grid (10, 8, 4) = 320 blocks, 256 thr, 56 KB LDS.
__global__ __launch_bounds__(256) void gram_kernel(const float* __restrict__ X,
                                                   const float* __restrict__ Wm,
                                                   float* __restrict__ G,
                                                   float* __restrict__ Ppart) {
    const int ti    = TI_MAP[blockIdx.x];
    const int tj    = TJ_MAP[blockIdx.x];
    const int batch = blockIdx.y;
    const int kq    = blockIdx.z;
    const bool diag = (ti == tj);

    const float* Xq = X + (size_t)batch * S * D + kq * KS;

    __shared__ _Float16 AhS[64][104], AlS[64][104], BhS[64][104], BlS[64][104];
    __shared__ float Ws[192][4];   // W slice for the fused X@W partial

    const int t    = threadIdx.x;
    const int srow = t >> 2;          // 0..63 staging row
    const int sk   = (t & 3) * 24;    // 24 floats (6 float4) per thread per chunk

    if (diag && t < 192)
        *(float4*)&Ws[t][0] = *(const float4*)(Wm + (size_t)(kq * KS + t) * 4);

    const float* pa = Xq + (size_t)(ti * 64 + srow) * D + sk;
    const float* pb = Xq + (size_t)(tj * 64 + srow) * D + sk;

    float4 va[6], vb[6], xva[6];
#pragma unroll
    for (int c = 0; c < 6; ++c) va[c] = *(const float4*)(pa + c * 4);
    if (!diag) {
#pragma unroll
        for (int c = 0; c < 6; ++c) vb[c] = *(const float4*)(pb + c * 4);
    }

    const int lane = t & 63;
    const int w    = t >> 6;          // 4 waves: rows (w>>1)*32, cols (w&1)*32
    const int rb   = (w >> 1) * 32;
    const int cb   = (w & 1) * 32;
    const int frow = lane & 15;
    const int fko  = (lane >> 4) * 8; // fragment k offset (8 halfs)

    f32x4 acc00 = {}, acc01 = {}, acc10 = {}, acc11 = {};
    float4 pacc = make_float4(0.f, 0.f, 0.f, 0.f);

    for (int ch = 0; ch < 2; ++ch) {
        if (ch) __syncthreads();      // previous chunk's LDS reads drained
#pragma unroll
        for (int c = 0; c < 6; ++c) {
            const int ko = sk + c * 4;
            const float4 a = va[c];
            half4v ha, la;
            ha.x = (_Float16)a.x; la.x = (_Float16)(a.x - (float)ha.x);
            ha.y = (_Float16)a.y; la.y = (_Float16)(a.y - (float)ha.y);
            ha.z = (_Float16)a.z; la.z = (_Float16)(a.z - (float)ha.z);
            ha.w = (_Float16)a.w; la.w = (_Float16)(a.w - (float)ha.w);
            *(half4v*)&AhS[srow][ko] = ha;
            *(half4v*)&AlS[srow][ko] = la;
        }
        if (!diag) {
#pragma unroll
            for (int c = 0; c < 6; ++c) {
                const int ko = sk + c * 4;
                const float4 bq = vb[c];
                half4v hb, lb;
                hb.x = (_Float16)bq.x; lb.x = (_Float16)(bq.x - (float)hb.x);
                hb.y = (_Float16)bq.y; lb.y = (_Float16)(bq.y - (float)hb.y);
                hb.z = (_Float16)bq.z; lb.z = (_Float16)(bq.z - (float)hb.z);
                hb.w = (_Float16)bq.w; lb.w = (_Float16)(bq.w - (float)hb.w);
                *(half4v*)&BhS[srow][ko] = hb;
                *(half4v*)&BlS[srow][ko] = lb;
            }
        } else {
#pragma unroll
            for (int c = 0; c < 6; ++c) xva[c] = va[c];   // stash for X@W
        }
        if (ch == 0) {                // register prefetch of chunk 1
#pragma unroll
            for (int c = 0; c < 6; ++c) va[c] = *(const float4*)(pa + CH + c * 4);
            if (!diag) {
#pragma unroll
                for (int c = 0; c < 6; ++c) vb[c] = *(const float4*)(pb + CH + c * 4);
            }
        }
        __syncthreads();

        // ---- fused X@W partial (diagonal blocks only) ----
        if (diag) {
#pragma unroll
            for (int c = 0; c < 6; ++c) {
                const float xf[4] = {xva[c].x, xva[c].y, xva[c].z, xva[c].w};
#pragma unroll
                for (int q = 0; q < 4; ++q) {
                    const float4 wq = *(const float4*)&Ws[ch * CH + sk + c * 4 + q][0];
                    pacc.x = fmaf(xf[q], wq.x, pacc.x);
                    pacc.y = fmaf(xf[q], wq.y, pacc.y);
                    pacc.z = fmaf(xf[q], wq.z, pacc.z);
                    pacc.w = fmaf(xf[q], wq.w, pacc.w);
                }
            }
        }

        // ---- MFMA: 2x2 16x16 frags per wave (8 ds_read -> 12 MFMA per ks) ----
        _Float16 (*Bh)[104] = diag ? AhS : BhS;
        _Float16 (*Bl)[104] = diag ? AlS : BlS;
#pragma unroll
        for (int ks = 0; ks < 3; ++ks) {
            const int k0 = ks * 32 + fko;
            const half8 ah0 = *(const half8*)&AhS[rb + frow][k0];
            const half8 al0 = *(const half8*)&AlS[rb + frow][k0];
            const half8 ah1 = *(const half8*)&AhS[rb + 16 + frow][k0];
            const half8 al1 = *(const half8*)&AlS[rb + 16 + frow][k0];
            const half8 bh0 = *(const half8*)&Bh[cb + frow][k0];
            const half8 bl0 = *(const half8*)&Bl[cb + frow][k0];
            const half8 bh1 = *(const half8*)&Bh[cb + 16 + frow][k0];
            const half8 bl1 = *(const half8*)&Bl[cb + 16 + frow][k0];
            acc00 = __builtin_amdgcn_mfma_f32_16x16x32_f16(ah0, bh0, acc00, 0, 0, 0);
            acc00 = __builtin_amdgcn_mfma_f32_16x16x32_f16(ah0, bl0, acc00, 0, 0, 0);
            acc00 = __builtin_amdgcn_mfma_f32_16x16x32_f16(al0, bh0, acc00, 0, 0, 0);
            acc01 = __builtin_amdgcn_mfma_f32_16x16x32_f16(ah0, bh1, acc01, 0, 0, 0);
            acc01 = __builtin_amdgcn_mfma_f32_16x16x32_f16(ah0, bl1, acc01, 0, 0, 0);
            acc01 = __builtin_amdgcn_mfma_f32_16x16x32_f16(al0, bh1, acc01, 0, 0, 0);
            acc10 = __builtin_amdgcn_mfma_f32_16x16x32_f16(ah1, bh0, acc10, 0, 0, 0);
            acc10 = __builtin_amdgcn_mfma_f32_16x16x32_f16(ah1, bl0, acc10, 0, 0, 0);
            acc10 = __builtin_amdgcn_mfma_f32_16x16x32_f16(al1, bh0, acc10, 0, 0, 0);
            acc11 = __builtin_amdgcn_mfma_f32_16x16x32_f16(ah1, bh1, acc11, 0, 0, 0);
            acc11 = __builtin_amdgcn_mfma_f32_16x16x32_f16(ah1, bl1, acc11, 0, 0, 0);
            acc11 = __builtin_amdgcn_mfma_f32_16x16x32_f16(al1, bh1, acc11, 0, 0, 0);
        }
    }

    if (diag) {
#pragma unroll
        for (int off = 1; off <= 2; off <<= 1) {     // 4-lane group = one row
            pacc.x += __shfl_xor(pacc.x, off);
            pacc.y += __shfl_xor(pacc.y, off);
            pacc.z += __shfl_xor(pacc.z, off);
            pacc.w += __shfl_xor(pacc.w, off);
        }
        if ((t & 3) == 0)
            *(float4*)(Ppart + (((size_t)batch * S + ti * 64 + srow) * KQ + kq) * 4) = pacc;
    }

    // C/D layout (m89-verified): col = lane&15, row = (lane>>4)*4 + reg.
    float* gout = G + ((size_t)(batch * S + ti * 64 + rb + (lane >> 4) * 4) * KQ + kq) * S
                    + tj * 64 + cb + frow;
#pragma unroll
    for (int r = 0; r < 4; ++r) {
        gout[(size_t)r * GROWS]                    = acc00[r];
        gout[(size_t)r * GROWS + 16]               = acc01[r];
        gout[(size_t)(16 + r) * GROWS]             = acc10[r];
        gout[(size_t)(16 + r) * GROWS + 16]        = acc11[r];
    }
}

// Per-b visibility test, byte-identical arithmetic to the r15/r16-validated
// body; result lands in block-local LDS instead of global memory.
__device__ __forceinline__ void vis_one(const float* __restrict__ G,
                                        float* __restrict__ wv_sh,
                                        int batch, int b, int lane) {
    const float* rbp = G + (size_t)(batch * S + b) * GROWS + 4 * lane;
    float4 s0 = make_float4(0.f, 0.f, 0.f, 0.f), s1 = s0, s2 = s0, s3 = s0;
    if (4 * lane <= b) {            // triangle: lanes past b contribute nothing
        s0 = *(const float4*)(rbp + (size_t)0 * S);
        s1 = *(const float4*)(rbp + (size_t)1 * S);
        s2 = *(const float4*)(rbp + (size_t)2 * S);
        s3 = *(const float4*)(rbp + (size_t)3 * S);
    }
    float4 gs;
    gs.x = (s0.x + s1.x) + (s2.x + s3.x);
    gs.y = (s0.y + s1.y) + (s2.y + s3.y);
    gs.z = (s0.z + s1.z) + (s2.z + s3.z);
    gs.w = (s0.w + s1.w) + (s2.w + s3.w);

    const int bq = b & 3;                       // wave-uniform component select
    float sel = (bq == 0) ? gs.x : ((bq == 1) ? gs.y : ((bq == 2) ? gs.z : gs.w));
    const float gb = __shfl(sel, b >> 2);
    const float g0 = __shfl(gs.x, 0);
    const float denom = (b > 0) ? (float)b : 1.0f;

    bool blocked = false;
    {
        const int c0 = 4 * lane;
#define VTEST(Q, GV) { const int c = c0 + (Q); \
        const float line = gb + ((g0 - gb) * (float)(b - c)) / denom; \
        if (c >= 1 && c < b && (GV) >= line) blocked = true; }
        VTEST(0, gs.x) VTEST(1, gs.y) VTEST(2, gs.z) VTEST(3, gs.w)
#undef VTEST
    }
    const bool visflag = (b >= 1) && !__any(blocked);

    if (lane == 0) wv_sh[b] = visflag ? 1.0f : 0.0f;
}

// Fused vis + head: ONE block per batch (1024 threads = 16 waves).
// Wave u computes visibility for b = u + 16j (j=0..15) into LDS (balanced
// guarded-lane load across waves), then after one __syncthreads the head
// (threads 0..255, arithmetic identical to r16) produces log_softmax -> out.
// Saves one dispatch + the global wv round-trip; no fences, no atomics.
__global__ __launch_bounds__(1024) void vishead_kernel(const float* __restrict__ G,
                                                       const float* __restrict__ Ppart,
                                                       float* __restrict__ out) {
    const int batch = blockIdx.x;
    const int t     = threadIdx.x;
    const int wave  = t >> 6;     // 0..15
    const int lane  = t & 63;

    __shared__ float wv_sh[S];
    __shared__ float4 lsh[4];

#pragma unroll
    for (int j = 0; j < 16; ++j)
        vis_one(G, wv_sh, batch, wave + 16 * j, lane);

    __syncthreads();

    // ---- head (threads 0..255; arithmetic identical to r16 head) ----
    float4 acc = make_float4(0.f, 0.f, 0.f, 0.f);
    if (t < S) {
        if (wv_sh[t] != 0.0f) {
            const float* pp = Ppart + ((size_t)batch * S + t) * (KQ * 4);
#pragma unroll
            for (int kq = 0; kq < KQ; ++kq) {
                const float4 p = *(const float4*)(pp + kq * 4);
                acc.x += p.x; acc.y += p.y; acc.z += p.z; acc.w += p.w;
            }
        }
#pragma unroll
        for (int off = 32; off; off >>= 1) {
            acc.x += __shfl_xor(acc.x, off);
            acc.y += __shfl_xor(acc.y, off);
            acc.z += __shfl_xor(acc.z, off);
            acc.w += __shfl_xor(acc.w, off);
        }
        if (lane == 0) lsh[wave] = acc;
    }
    __syncthreads();

    if (t == 0) {
        const float l0 = ((lsh[0].x + lsh[1].x) + (lsh[2].x + lsh[3].x));
        const float l1 = ((lsh[0].y + lsh[1].y) + (lsh[2].y + lsh[3].y));
        const float l2 = ((lsh[0].z + lsh[1].z) + (lsh[2].z + lsh[3].z));
        const float l3 = ((lsh[0].w + lsh[1].w) + (lsh[2].w + lsh[3].w));
        const float m = fmaxf(fmaxf(l0, l1), fmaxf(l2, l3));
        const float lse = logf(expf(l0 - m) + expf(l1 - m) + expf(l2 - m) + expf(l3 - m));
        out[batch * 4 + 0] = l0 - m - lse;
        out[batch * 4 + 1] = l1 - m - lse;
        out[batch * 4 + 2] = l2 - m - lse;
        out[batch * 4 + 3] = l3 - m - lse;
    }
}

extern "C" void kernel_launch(void* const* d_in, const int* in_sizes, int n_in,
                              void* d_out, int out_size, void* d_ws, size_t ws_size,
                              hipStream_t stream) {
    const float* X  = (const float*)d_in[0];   // [8, 256, 768] fp32
    const float* Wm = (const float*)d_in[1];   // [768, 4] fp32
    float* out = (float*)d_out;                // [8, 4] fp32

    float* ws = (float*)d_ws;
    float* Ppart = ws;                         // 8*256*4*4 = 32768 floats
    float* G     = ws + 32768;                 // 8*256*4*256 = 2.10M floats (8.4 MB)

    gram_kernel   <<<dim3(10, 8, 4), 256,  0, stream>>>(X, Wm, G, Ppart);
    vishead_kernel<<<8,              1024, 0, stream>>>(G, Ppart, out);
}

// Round 18
// 27.428 us; speedup vs baseline: 1.0580x; 1.0580x over previous
//
#include <hip/hip_runtime.h>
#include <hip/hip_bf16.h>

constexpr int S  = 256;
constexpr int D  = 768;
constexpr int KQ = 2;          // K slices
constexpr int KS = D / KQ;     // 384 per slice
constexpr int CH = 96;         // staged chunk width
constexpr int NCH = KS / CH;   // 4 chunks per slice
constexpr int GROWS = KQ * S;  // 512 floats: G[((batch*256+row)*2+kq)*256+col]

typedef _Float16 half8  __attribute__((ext_vector_type(8)));
typedef _Float16 half4v __attribute__((ext_vector_type(4)));
typedef float    f32x4  __attribute__((ext_vector_type(4)));

// Lower-triangle 64x64 tile positions (ti >= tj) of the 4x4 tile grid.
__device__ const int TI_MAP[10] = {0,1,1,2,2,2,3,3,3,3};
__device__ const int TJ_MAP[10] = {0,0,1,0,1,2,0,1,2,3};

// Gram via MFMA (r15-validated inner loop): triangle tiles, fused fp16 hi/lo
// split, diag B->A alias, fused X@W partials, 2x2 micro-tile. r18: KQ=2 with
// four register-prefetched 96-chunks -> grid (10, 8, 2) = 160 blocks, 256 thr.
__global__ __launch_bounds__(256) void gram_kernel(const float* __restrict__ X,
                                                   const float* __restrict__ Wm,
                                                   float* __restrict__ G,
                                                   float* __restrict__ Ppart) {
    const int ti    = TI_MAP[blockIdx.x];
    const int tj    = TJ_MAP[blockIdx.x];
    const int batch = blockIdx.y;
    const int kq    = blockIdx.z;
    const bool diag = (ti == tj);

    const float* Xq = X + (size_t)batch * S * D + kq * KS;

    __shared__ _Float16 AhS[64][104], AlS[64][104], BhS[64][104], BlS[64][104];
    __shared__ float Ws[KS][4];    // W slice for the fused X@W partial (6 KB)

    const int t    = threadIdx.x;
    const int srow = t >> 2;          // 0..63 staging row
    const int sk   = (t & 3) * 24;    // 24 floats (6 float4) per thread per chunk

    if (diag) {
#pragma unroll
        for (int r = 0; r < 2; ++r) {
            const int idx = t + 256 * r;
            if (idx < KS)
                *(float4*)&Ws[idx][0] = *(const float4*)(Wm + (size_t)(kq * KS + idx) * 4);
        }
    }

    const float* pa = Xq + (size_t)(ti * 64 + srow) * D + sk;
    const float* pb = Xq + (size_t)(tj * 64 + srow) * D + sk;

    float4 va[6], vb[6], xva[6];
#pragma unroll
    for (int c = 0; c < 6; ++c) va[c] = *(const float4*)(pa + c * 4);
    if (!diag) {
#pragma unroll
        for (int c = 0; c < 6; ++c) vb[c] = *(const float4*)(pb + c * 4);
    }

    const int lane = t & 63;
    const int w    = t >> 6;          // 4 waves: rows (w>>1)*32, cols (w&1)*32
    const int rb   = (w >> 1) * 32;
    const int cb   = (w & 1) * 32;
    const int frow = lane & 15;
    const int fko  = (lane >> 4) * 8; // fragment k offset (8 halfs)

    f32x4 acc00 = {}, acc01 = {}, acc10 = {}, acc11 = {};
    float4 pacc = make_float4(0.f, 0.f, 0.f, 0.f);

#pragma unroll
    for (int ch = 0; ch < NCH; ++ch) {
        if (ch) __syncthreads();      // previous chunk's LDS reads drained
#pragma unroll
        for (int c = 0; c < 6; ++c) {
            const int ko = sk + c * 4;
            const float4 a = va[c];
            half4v ha, la;
            ha.x = (_Float16)a.x; la.x = (_Float16)(a.x - (float)ha.x);
            ha.y = (_Float16)a.y; la.y = (_Float16)(a.y - (float)ha.y);
            ha.z = (_Float16)a.z; la.z = (_Float16)(a.z - (float)ha.z);
            ha.w = (_Float16)a.w; la.w = (_Float16)(a.w - (float)ha.w);
            *(half4v*)&AhS[srow][ko] = ha;
            *(half4v*)&AlS[srow][ko] = la;
        }
        if (!diag) {
#pragma unroll
            for (int c = 0; c < 6; ++c) {
                const int ko = sk + c * 4;
                const float4 bq = vb[c];
                half4v hb, lb;
                hb.x = (_Float16)bq.x; lb.x = (_Float16)(bq.x - (float)hb.x);
                hb.y = (_Float16)bq.y; lb.y = (_Float16)(bq.y - (float)hb.y);
                hb.z = (_Float16)bq.z; lb.z = (_Float16)(bq.z - (float)hb.z);
                hb.w = (_Float16)bq.w; lb.w = (_Float16)(bq.w - (float)hb.w);
                *(half4v*)&BhS[srow][ko] = hb;
                *(half4v*)&BlS[srow][ko] = lb;
            }
        } else {
#pragma unroll
            for (int c = 0; c < 6; ++c) xva[c] = va[c];   // stash for X@W
        }
        if (ch + 1 < NCH) {           // register prefetch of next chunk
#pragma unroll
            for (int c = 0; c < 6; ++c)
                va[c] = *(const float4*)(pa + (ch + 1) * CH + c * 4);
            if (!diag) {
#pragma unroll
                for (int c = 0; c < 6; ++c)
                    vb[c] = *(const float4*)(pb + (ch + 1) * CH + c * 4);
            }
        }
        __syncthreads();

        // ---- fused X@W partial (diagonal blocks only) ----
        if (diag) {
#pragma unroll
            for (int c = 0; c < 6; ++c) {
                const float xf[4] = {xva[c].x, xva[c].y, xva[c].z, xva[c].w};
#pragma unroll
                for (int q = 0; q < 4; ++q) {
                    const float4 wq = *(const float4*)&Ws[ch * CH + sk + c * 4 + q][0];
                    pacc.x = fmaf(xf[q], wq.x, pacc.x);
                    pacc.y = fmaf(xf[q], wq.y, pacc.y);
                    pacc.z = fmaf(xf[q], wq.z, pacc.z);
                    pacc.w = fmaf(xf[q], wq.w, pacc.w);
                }
            }
        }

        // ---- MFMA: 2x2 16x16 frags per wave (8 ds_read -> 12 MFMA per ks) ----
        _Float16 (*Bh)[104] = diag ? AhS : BhS;
        _Float16 (*Bl)[104] = diag ? AlS : BlS;
#pragma unroll
        for (int ks = 0; ks < 3; ++ks) {
            const int k0 = ks * 32 + fko;
            const half8 ah0 = *(const half8*)&AhS[rb + frow][k0];
            const half8 al0 = *(const half8*)&AlS[rb + frow][k0];
            const half8 ah1 = *(const half8*)&AhS[rb + 16 + frow][k0];
            const half8 al1 = *(const half8*)&AlS[rb + 16 + frow][k0];
            const half8 bh0 = *(const half8*)&Bh[cb + frow][k0];
            const half8 bl0 = *(const half8*)&Bl[cb + frow][k0];
            const half8 bh1 = *(const half8*)&Bh[cb + 16 + frow][k0];
            const half8 bl1 = *(const half8*)&Bl[cb + 16 + frow][k0];
            acc00 = __builtin_amdgcn_mfma_f32_16x16x32_f16(ah0, bh0, acc00, 0, 0, 0);
            acc00 = __builtin_amdgcn_mfma_f32_16x16x32_f16(ah0, bl0, acc00, 0, 0, 0);
            acc00 = __builtin_amdgcn_mfma_f32_16x16x32_f16(al0, bh0, acc00, 0, 0, 0);
            acc01 = __builtin_amdgcn_mfma_f32_16x16x32_f16(ah0, bh1, acc01, 0, 0, 0);
            acc01 = __builtin_amdgcn_mfma_f32_16x16x32_f16(ah0, bl1, acc01, 0, 0, 0);
            acc01 = __builtin_amdgcn_mfma_f32_16x16x32_f16(al0, bh1, acc01, 0, 0, 0);
            acc10 = __builtin_amdgcn_mfma_f32_16x16x32_f16(ah1, bh0, acc10, 0, 0, 0);
            acc10 = __builtin_amdgcn_mfma_f32_16x16x32_f16(ah1, bl0, acc10, 0, 0, 0);
            acc10 = __builtin_amdgcn_mfma_f32_16x16x32_f16(al1, bh0, acc10, 0, 0, 0);
            acc11 = __builtin_amdgcn_mfma_f32_16x16x32_f16(ah1, bh1, acc11, 0, 0, 0);
            acc11 = __builtin_amdgcn_mfma_f32_16x16x32_f16(ah1, bl1, acc11, 0, 0, 0);
            acc11 = __builtin_amdgcn_mfma_f32_16x16x32_f16(al1, bh1, acc11, 0, 0, 0);
        }
    }

    if (diag) {
#pragma unroll
        for (int off = 1; off <= 2; off <<= 1) {     // 4-lane group = one row
            pacc.x += __shfl_xor(pacc.x, off);
            pacc.y += __shfl_xor(pacc.y, off);
            pacc.z += __shfl_xor(pacc.z, off);
            pacc.w += __shfl_xor(pacc.w, off);
        }
        if ((t & 3) == 0)
            *(float4*)(Ppart + (((size_t)batch * S + ti * 64 + srow) * KQ + kq) * 4) = pacc;
    }

    // C/D layout (m89-verified): col = lane&15, row = (lane>>4)*4 + reg.
    float* gout = G + ((size_t)(batch * S + ti * 64 + rb + (lane >> 4) * 4) * KQ + kq) * S
                    + tj * 64 + cb + frow;
#pragma unroll
    for (int r = 0; r < 4; ++r) {
        gout[(size_t)r * GROWS]             = acc00[r];
        gout[(size_t)r * GROWS + 16]        = acc01[r];
        gout[(size_t)(16 + r) * GROWS]      = acc10[r];
        gout[(size_t)(16 + r) * GROWS + 16] = acc11[r];
    }
}

// Fused vis + head: one block per batch, 1024 threads = 16 waves.
// Wave u tests b = u + 16j in a PLAIN loop (unroll 4): ~2 float4 in flight
// per iteration keeps VGPR low (r17 post-mortem: full unroll forced
// serialization/spill at the 128-VGPR launch bound); 16 waves/CU of TLP
// hide the L2 latency. vis arithmetic identical to the validated body.
__global__ __launch_bounds__(1024) void vishead_kernel(const float* __restrict__ G,
                                                       const float* __restrict__ Ppart,
                                                       float* __restrict__ out) {
    const int batch = blockIdx.x;
    const int t     = threadIdx.x;
    const int wave  = t >> 6;     // 0..15
    const int lane  = t & 63;

    __shared__ float wv_sh[S];
    __shared__ float4 lsh[4];

#pragma unroll 4
    for (int j = 0; j < 16; ++j) {
        const int b = wave + 16 * j;
        const float* rbp = G + (size_t)(batch * S + b) * GROWS + 4 * lane;
        float4 s0 = make_float4(0.f, 0.f, 0.f, 0.f), s1 = s0;
        if (4 * lane <= b) {        // triangle guard
            s0 = *(const float4*)(rbp);
            s1 = *(const float4*)(rbp + S);
        }
        float4 gs;
        gs.x = s0.x + s1.x;
        gs.y = s0.y + s1.y;
        gs.z = s0.z + s1.z;
        gs.w = s0.w + s1.w;

        const int bq = b & 3;                   // wave-uniform component select
        float sel = (bq == 0) ? gs.x : ((bq == 1) ? gs.y : ((bq == 2) ? gs.z : gs.w));
        const float gb = __shfl(sel, b >> 2);
        const float g0 = __shfl(gs.x, 0);
        const float denom = (b > 0) ? (float)b : 1.0f;

        bool blocked = false;
        {
            const int c0 = 4 * lane;
#define VTEST(Q, GV) { const int c = c0 + (Q); \
            const float line = gb + ((g0 - gb) * (float)(b - c)) / denom; \
            if (c >= 1 && c < b && (GV) >= line) blocked = true; }
            VTEST(0, gs.x) VTEST(1, gs.y) VTEST(2, gs.z) VTEST(3, gs.w)
#undef VTEST
        }
        const bool visflag = (b >= 1) && !__any(blocked);
        if (lane == 0) wv_sh[b] = visflag ? 1.0f : 0.0f;
    }

    __syncthreads();

    // ---- head (threads 0..255; arithmetic identical to r16) ----
    float4 acc = make_float4(0.f, 0.f, 0.f, 0.f);
    if (t < S) {
        if (wv_sh[t] != 0.0f) {
            const float* pp = Ppart + ((size_t)batch * S + t) * (KQ * 4);
#pragma unroll
            for (int kq = 0; kq < KQ; ++kq) {
                const float4 p = *(const float4*)(pp + kq * 4);
                acc.x += p.x; acc.y += p.y; acc.z += p.z; acc.w += p.w;
            }
        }
#pragma unroll
        for (int off = 32; off; off >>= 1) {
            acc.x += __shfl_xor(acc.x, off);
            acc.y += __shfl_xor(acc.y, off);
            acc.z += __shfl_xor(acc.z, off);
            acc.w += __shfl_xor(acc.w, off);
        }
        if (lane == 0) lsh[wave] = acc;
    }
    __syncthreads();

    if (t == 0) {
        const float l0 = ((lsh[0].x + lsh[1].x) + (lsh[2].x + lsh[3].x));
        const float l1 = ((lsh[0].y + lsh[1].y) + (lsh[2].y + lsh[3].y));
        const float l2 = ((lsh[0].z + lsh[1].z) + (lsh[2].z + lsh[3].z));
        const float l3 = ((lsh[0].w + lsh[1].w) + (lsh[2].w + lsh[3].w));
        const float m = fmaxf(fmaxf(l0, l1), fmaxf(l2, l3));
        const float lse = logf(expf(l0 - m) + expf(l1 - m) + expf(l2 - m) + expf(l3 - m));
        out[batch * 4 + 0] = l0 - m - lse;
        out[batch * 4 + 1] = l1 - m - lse;
        out[batch * 4 + 2] = l2 - m - lse;
        out[batch * 4 + 3] = l3 - m - lse;
    }
}

extern "C" void kernel_launch(void* const* d_in, const int* in_sizes, int n_in,
                              void* d_out, int out_size, void* d_ws, size_t ws_size,
                              hipStream_t stream) {
    const float* X  = (const float*)d_in[0];   // [8, 256, 768] fp32
    const float* Wm = (const float*)d_in[1];   // [768, 4] fp32
    float* out = (float*)d_out;                // [8, 4] fp32

    float* ws = (float*)d_ws;
    float* Ppart = ws;                         // 8*256*2*4 = 16384 floats
    float* G     = ws + 16384;                 // 8*256*2*256 = 1.05M floats (4.2 MB)

    gram_kernel   <<<dim3(10, 8, 2), 256,  0, stream>>>(X, Wm, G, Ppart);
    vishead_kernel<<<8,              1024, 0, stream>>>(G, Ppart, out);
}

// Round 19
// 18.187 us; speedup vs baseline: 1.5956x; 1.5081x over previous
//
#include <hip/hip_runtime.h>
#include <hip/hip_bf16.h>

constexpr int S  = 256;
constexpr int D  = 768;
constexpr int KQ = 4;          // K slices
constexpr int KS = D / KQ;     // 192 per slice
constexpr int CH = 96;         // staged chunk width (2 chunks per slice)
constexpr int GROWS = KQ * S;  // 1024 floats: G[((batch*256+row)*4+kq)*256+col]

typedef _Float16 half8  __attribute__((ext_vector_type(8)));
typedef _Float16 half4v __attribute__((ext_vector_type(4)));
typedef float    f32x4  __attribute__((ext_vector_type(4)));

// Lower-triangle 64x64 tile positions (ti >= tj) of the 4x4 tile grid.
__device__ const int TI_MAP[10] = {0,1,1,2,2,2,3,3,3,3};
__device__ const int TJ_MAP[10] = {0,0,1,0,1,2,0,1,2,3};

// Gram via MFMA (r15-validated verbatim): triangle tiles, fused fp16 hi/lo
// split, diag B->A alias, fused X@W partials, 2x2 micro-tile, KQ=4 with two
// register-prefetched 96-chunks. Grid (10, 8, 4) = 320 blocks, 256 thr, 56 KB LDS.
__global__ __launch_bounds__(256) void gram_kernel(const float* __restrict__ X,
                                                   const float* __restrict__ Wm,
                                                   float* __restrict__ G,
                                                   float* __restrict__ Ppart) {
    const int ti    = TI_MAP[blockIdx.x];
    const int tj    = TJ_MAP[blockIdx.x];
    const int batch = blockIdx.y;
    const int kq    = blockIdx.z;
    const bool diag = (ti == tj);

    const float* Xq = X + (size_t)batch * S * D + kq * KS;

    __shared__ _Float16 AhS[64][104], AlS[64][104], BhS[64][104], BlS[64][104];
    __shared__ float Ws[192][4];   // W slice for the fused X@W partial

    const int t    = threadIdx.x;
    const int srow = t >> 2;          // 0..63 staging row
    const int sk   = (t & 3) * 24;    // 24 floats (6 float4) per thread per chunk

    if (diag && t < 192)
        *(float4*)&Ws[t][0] = *(const float4*)(Wm + (size_t)(kq * KS + t) * 4);

    const float* pa = Xq + (size_t)(ti * 64 + srow) * D + sk;
    const float* pb = Xq + (size_t)(tj * 64 + srow) * D + sk;

    float4 va[6], vb[6], xva[6];
#pragma unroll
    for (int c = 0; c < 6; ++c) va[c] = *(const float4*)(pa + c * 4);
    if (!diag) {
#pragma unroll
        for (int c = 0; c < 6; ++c) vb[c] = *(const float4*)(pb + c * 4);
    }

    const int lane = t & 63;
    const int w    = t >> 6;          // 4 waves: rows (w>>1)*32, cols (w&1)*32
    const int rb   = (w >> 1) * 32;
    const int cb   = (w & 1) * 32;
    const int frow = lane & 15;
    const int fko  = (lane >> 4) * 8; // fragment k offset (8 halfs)

    f32x4 acc00 = {}, acc01 = {}, acc10 = {}, acc11 = {};
    float4 pacc = make_float4(0.f, 0.f, 0.f, 0.f);

    for (int ch = 0; ch < 2; ++ch) {
        if (ch) __syncthreads();      // previous chunk's LDS reads drained
#pragma unroll
        for (int c = 0; c < 6; ++c) {
            const int ko = sk + c * 4;
            const float4 a = va[c];
            half4v ha, la;
            ha.x = (_Float16)a.x; la.x = (_Float16)(a.x - (float)ha.x);
            ha.y = (_Float16)a.y; la.y = (_Float16)(a.y - (float)ha.y);
            ha.z = (_Float16)a.z; la.z = (_Float16)(a.z - (float)ha.z);
            ha.w = (_Float16)a.w; la.w = (_Float16)(a.w - (float)ha.w);
            *(half4v*)&AhS[srow][ko] = ha;
            *(half4v*)&AlS[srow][ko] = la;
        }
        if (!diag) {
#pragma unroll
            for (int c = 0; c < 6; ++c) {
                const int ko = sk + c * 4;
                const float4 bq = vb[c];
                half4v hb, lb;
                hb.x = (_Float16)bq.x; lb.x = (_Float16)(bq.x - (float)hb.x);
                hb.y = (_Float16)bq.y; lb.y = (_Float16)(bq.y - (float)hb.y);
                hb.z = (_Float16)bq.z; lb.z = (_Float16)(bq.z - (float)hb.z);
                hb.w = (_Float16)bq.w; lb.w = (_Float16)(bq.w - (float)hb.w);
                *(half4v*)&BhS[srow][ko] = hb;
                *(half4v*)&BlS[srow][ko] = lb;
            }
        } else {
#pragma unroll
            for (int c = 0; c < 6; ++c) xva[c] = va[c];   // stash for X@W
        }
        if (ch == 0) {                // register prefetch of chunk 1
#pragma unroll
            for (int c = 0; c < 6; ++c) va[c] = *(const float4*)(pa + CH + c * 4);
            if (!diag) {
#pragma unroll
                for (int c = 0; c < 6; ++c) vb[c] = *(const float4*)(pb + CH + c * 4);
            }
        }
        __syncthreads();

        // ---- fused X@W partial (diagonal blocks only) ----
        if (diag) {
#pragma unroll
            for (int c = 0; c < 6; ++c) {
                const float xf[4] = {xva[c].x, xva[c].y, xva[c].z, xva[c].w};
#pragma unroll
                for (int q = 0; q < 4; ++q) {
                    const float4 wq = *(const float4*)&Ws[ch * CH + sk + c * 4 + q][0];
                    pacc.x = fmaf(xf[q], wq.x, pacc.x);
                    pacc.y = fmaf(xf[q], wq.y, pacc.y);
                    pacc.z = fmaf(xf[q], wq.z, pacc.z);
                    pacc.w = fmaf(xf[q], wq.w, pacc.w);
                }
            }
        }

        // ---- MFMA: 2x2 16x16 frags per wave (8 ds_read -> 12 MFMA per ks) ----
        _Float16 (*Bh)[104] = diag ? AhS : BhS;
        _Float16 (*Bl)[104] = diag ? AlS : BlS;
#pragma unroll
        for (int ks = 0; ks < 3; ++ks) {
            const int k0 = ks * 32 + fko;
            const half8 ah0 = *(const half8*)&AhS[rb + frow][k0];
            const half8 al0 = *(const half8*)&AlS[rb + frow][k0];
            const half8 ah1 = *(const half8*)&AhS[rb + 16 + frow][k0];
            const half8 al1 = *(const half8*)&AlS[rb + 16 + frow][k0];
            const half8 bh0 = *(const half8*)&Bh[cb + frow][k0];
            const half8 bl0 = *(const half8*)&Bl[cb + frow][k0];
            const half8 bh1 = *(const half8*)&Bh[cb + 16 + frow][k0];
            const half8 bl1 = *(const half8*)&Bl[cb + 16 + frow][k0];
            acc00 = __builtin_amdgcn_mfma_f32_16x16x32_f16(ah0, bh0, acc00, 0, 0, 0);
            acc00 = __builtin_amdgcn_mfma_f32_16x16x32_f16(ah0, bl0, acc00, 0, 0, 0);
            acc00 = __builtin_amdgcn_mfma_f32_16x16x32_f16(al0, bh0, acc00, 0, 0, 0);
            acc01 = __builtin_amdgcn_mfma_f32_16x16x32_f16(ah0, bh1, acc01, 0, 0, 0);
            acc01 = __builtin_amdgcn_mfma_f32_16x16x32_f16(ah0, bl1, acc01, 0, 0, 0);
            acc01 = __builtin_amdgcn_mfma_f32_16x16x32_f16(al0, bh1, acc01, 0, 0, 0);
            acc10 = __builtin_amdgcn_mfma_f32_16x16x32_f16(ah1, bh0, acc10, 0, 0, 0);
            acc10 = __builtin_amdgcn_mfma_f32_16x16x32_f16(ah1, bl0, acc10, 0, 0, 0);
            acc10 = __builtin_amdgcn_mfma_f32_16x16x32_f16(al1, bh0, acc10, 0, 0, 0);
            acc11 = __builtin_amdgcn_mfma_f32_16x16x32_f16(ah1, bh1, acc11, 0, 0, 0);
            acc11 = __builtin_amdgcn_mfma_f32_16x16x32_f16(ah1, bl1, acc11, 0, 0, 0);
            acc11 = __builtin_amdgcn_mfma_f32_16x16x32_f16(al1, bh1, acc11, 0, 0, 0);
        }
    }

    if (diag) {
#pragma unroll
        for (int off = 1; off <= 2; off <<= 1) {     // 4-lane group = one row
            pacc.x += __shfl_xor(pacc.x, off);
            pacc.y += __shfl_xor(pacc.y, off);
            pacc.z += __shfl_xor(pacc.z, off);
            pacc.w += __shfl_xor(pacc.w, off);
        }
        if ((t & 3) == 0)
            *(float4*)(Ppart + (((size_t)batch * S + ti * 64 + srow) * KQ + kq) * 4) = pacc;
    }

    // C/D layout (m89-verified): col = lane&15, row = (lane>>4)*4 + reg.
    float* gout = G + ((size_t)(batch * S + ti * 64 + rb + (lane >> 4) * 4) * KQ + kq) * S
                    + tj * 64 + cb + frow;
#pragma unroll
    for (int r = 0; r < 4; ++r) {
        gout[(size_t)r * GROWS]                    = acc00[r];
        gout[(size_t)r * GROWS + 16]               = acc01[r];
        gout[(size_t)(16 + r) * GROWS]             = acc10[r];
        gout[(size_t)(16 + r) * GROWS + 16]        = acc11[r];
    }
}

// Per-b visibility test, byte-identical arithmetic to r15's vis body.
__device__ __forceinline__ void vis_one(const float* __restrict__ G,
                                        float* __restrict__ wv,
                                        int batch, int b, int lane) {
    const float* rbp = G + (size_t)(batch * S + b) * GROWS + 4 * lane;
    float4 s0 = make_float4(0.f, 0.f, 0.f, 0.f), s1 = s0, s2 = s0, s3 = s0;
    if (4 * lane <= b) {            // triangle: lanes past b contribute nothing
        s0 = *(const float4*)(rbp + (size_t)0 * S);
        s1 = *(const float4*)(rbp + (size_t)1 * S);
        s2 = *(const float4*)(rbp + (size_t)2 * S);
        s3 = *(const float4*)(rbp + (size_t)3 * S);
    }
    float4 gs;
    gs.x = (s0.x + s1.x) + (s2.x + s3.x);
    gs.y = (s0.y + s1.y) + (s2.y + s3.y);
    gs.z = (s0.z + s1.z) + (s2.z + s3.z);
    gs.w = (s0.w + s1.w) + (s2.w + s3.w);

    const int bq = b & 3;                       // wave-uniform component select
    float sel = (bq == 0) ? gs.x : ((bq == 1) ? gs.y : ((bq == 2) ? gs.z : gs.w));
    const float gb = __shfl(sel, b >> 2);
    const float g0 = __shfl(gs.x, 0);
    const float denom = (b > 0) ? (float)b : 1.0f;

    bool blocked = false;
    {
        const int c0 = 4 * lane;
#define VTEST(Q, GV) { const int c = c0 + (Q); \
        const float line = gb + ((g0 - gb) * (float)(b - c)) / denom; \
        if (c >= 1 && c < b && (GV) >= line) blocked = true; }
        VTEST(0, gs.x) VTEST(1, gs.y) VTEST(2, gs.z) VTEST(3, gs.w)
#undef VTEST
    }
    const bool visflag = (b >= 1) && !__any(blocked);

    if (lane == 0) wv[batch * S + b] = visflag ? 1.0f : 0.0f;
}

// Vis, load-balanced: wave u handles b = u (short row) AND b = 255-u (long row)
// -> every wave reads ~65 guarded lane-slots; grid (32, 8) = 256 blocks.
__global__ __launch_bounds__(256) void vis_kernel(const float* __restrict__ G,
                                                  float* __restrict__ wv) {
    const int batch = blockIdx.y;
    const int wave  = threadIdx.x >> 6;
    const int lane  = threadIdx.x & 63;
    const int u     = blockIdx.x * 4 + wave;    // 0..127

    vis_one(G, wv, batch, u, lane);
    vis_one(G, wv, batch, 255 - u, lane);
}

// Head: logits_k = sum_s wv_s * sum_kq Ppart[s][kq][k]; log_softmax.
// Grid 8 blocks x 256 threads; thread t owns position s = t (64 B contiguous).
__global__ __launch_bounds__(256) void head_kernel(const float* __restrict__ Ppart,
                                                   const float* __restrict__ wv,
                                                   float* __restrict__ out) {
    const int batch = blockIdx.x;
    const int t     = threadIdx.x;
    const int wave  = t >> 6;
    const int lane  = t & 63;

    float4 acc = make_float4(0.f, 0.f, 0.f, 0.f);
    if (wv[batch * S + t] != 0.0f) {
        const float* pp = Ppart + ((size_t)batch * S + t) * (KQ * 4);
#pragma unroll
        for (int kq = 0; kq < KQ; ++kq) {
            const float4 p = *(const float4*)(pp + kq * 4);
            acc.x += p.x; acc.y += p.y; acc.z += p.z; acc.w += p.w;
        }
    }
#pragma unroll
    for (int off = 32; off; off >>= 1) {
        acc.x += __shfl_xor(acc.x, off);
        acc.y += __shfl_xor(acc.y, off);
        acc.z += __shfl_xor(acc.z, off);
        acc.w += __shfl_xor(acc.w, off);
    }

    __shared__ float4 lsh[4];
    if (lane == 0) lsh[wave] = acc;
    __syncthreads();

    if (t == 0) {
        const float l0 = ((lsh[0].x + lsh[1].x) + (lsh[2].x + lsh[3].x));
        const float l1 = ((lsh[0].y + lsh[1].y) + (lsh[2].y + lsh[3].y));
        const float l2 = ((lsh[0].z + lsh[1].z) + (lsh[2].z + lsh[3].z));
        const float l3 = ((lsh[0].w + lsh[1].w) + (lsh[2].w + lsh[3].w));
        const float m = fmaxf(fmaxf(l0, l1), fmaxf(l2, l3));
        const float lse = logf(expf(l0 - m) + expf(l1 - m) + expf(l2 - m) + expf(l3 - m));
        out[batch * 4 + 0] = l0 - m - lse;
        out[batch * 4 + 1] = l1 - m - lse;
        out[batch * 4 + 2] = l2 - m - lse;
        out[batch * 4 + 3] = l3 - m - lse;
    }
}

extern "C" void kernel_launch(void* const* d_in, const int* in_sizes, int n_in,
                              void* d_out, int out_size, void* d_ws, size_t ws_size,
                              hipStream_t stream) {
    const float* X  = (const float*)d_in[0];   // [8, 256, 768] fp32
    const float* Wm = (const float*)d_in[1];   // [768, 4] fp32
    float* out = (float*)d_out;                // [8, 4] fp32

    float* ws = (float*)d_ws;
    float* Ppart = ws;                         // 8*256*4*4 = 32768 floats
    float* wv    = ws + 32768;                 // 2048 floats
    float* G     = ws + 34816;                 // 8*256*4*256 = 2.10M floats (8.4 MB)

    gram_kernel<<<dim3(10, 8, 4), 256, 0, stream>>>(X, Wm, G, Ppart);
    vis_kernel <<<dim3(32, 8),    256, 0, stream>>>(G, wv);
    head_kernel<<<8,              256, 0, stream>>>(Ppart, wv, out);
}